// Round 14
// baseline (6063.353 us; speedup 1.0000x reference)
//
#include <hip/hip_runtime.h>
#include <hip/hip_fp16.h>

// IGIRNN persistent-scan kernel, round 14 = round 8 (3.08ms, best of 6
// structures) with ONE surgical change: PACKED FLAGS.
// Diagnosis: r8 polls touch 16 distinct 64B flag lines per wave per loop
// iter -> ~7 TB/s of continuous LLC poll traffic, contending with the
// publish/gather RTs (the unexplained 2x over the RT model). r13 proved
// exchange is 100% LLC-served (FETCH flat while logical volume doubled).
// Change: group's 64 flags packed at 4B stride (4 cachelines); all 64
// lanes poll one flag each; wave checks its 16-writer subset via
// ballot&mask. Poll traffic /4. Writer: same store, packed address
// (16 dword stores/line merge at LLC; sc0 sc1 has no line ownership).
// Everything else -- roles, gather asm, drain-before-flag, barrier,
// LDS layout -- byte-identical to r8.

#define BB 128
#define TT 1024
#define ID 256
#define HH 1024

using f16   = _Float16;
using f16x8 = __attribute__((ext_vector_type(8))) _Float16;
using f32x4 = __attribute__((ext_vector_type(4))) float;
typedef unsigned long long u64;

// LDS (bytes)
#define OFF_X    0        // x   [2][16][512B] f16, SWZ     = 16384
#define OFF_GX   16384    // gx  [2][4][272] f32            = 8704
#define OFF_GH   25088    // ghT [2][2][4][272] f32         = 17408
#define LDS_SIZE 42496

#define SWZ(row, kbyte) ((kbyte) ^ (((row) & 3) << 4))
#define MFMA16(a, b, c) __builtin_amdgcn_mfma_f32_16x16x32_f16(a, b, c, 0, 0, 0)

static __device__ __forceinline__ void store4h(f16* dst, float a, float b, float c, float d) {
  union { f16 h[4]; u64 u; } p;
  p.h[0] = (f16)a; p.h[1] = (f16)b; p.h[2] = (f16)c; p.h[3] = (f16)d;
  *reinterpret_cast<u64*>(dst) = p.u;
}

static __device__ __forceinline__ f16x8 cvt8(float4 a, float4 b) {
  f16x8 r;
  r[0] = (f16)a.x; r[1] = (f16)a.y; r[2] = (f16)a.z; r[3] = (f16)a.w;
  r[4] = (f16)b.x; r[5] = (f16)b.y; r[6] = (f16)b.z; r[7] = (f16)b.w;
  return r;
}

static __device__ __forceinline__ void put_tile(float* dst, f32x4 v, int lane) {
  const int c = lane & 15, r4 = (lane >> 4) * 4;
  #pragma unroll
  for (int r = 0; r < 4; ++r) dst[(r4 + r) * 17 + c] = v[r];
}

__global__ __launch_bounds__(256, 1) void rnn_core(
    const float* __restrict__ x, const float* __restrict__ Wx, const float* __restrict__ bx,
    const float* __restrict__ Wh, const float* __restrict__ bh,
    f16* __restrict__ hbuf,      // [2 slot][8 grp][32 wg][1KB chunk] = 1MB
    float* __restrict__ hfin,    // [128][1024] f32
    int* __restrict__ flags)     // PACKED: [8 grp][64] ints (256B/group)
{
  extern __shared__ char lds[];
  char*  xbuf = lds + OFF_X;
  float* gxch = (float*)(lds + OFF_GX);   // [2][4][272], q = gate*2 + nt
  float* ghT  = (float*)(lds + OFF_GH);   // [2][2][4][272]: [parity][nt][src]

  const int tid  = threadIdx.x;
  const int lane = tid & 63;
  const int w    = tid >> 6;
  const int g    = blockIdx.x & 7;
  const int cw   = blockIdx.x >> 3;
  const int b0   = g * 16;
  const int j0   = cw * 32;
  const int col  = lane & 15;
  const int quad = lane >> 4;
  const int row4 = quad * 4;
  const int nt   = w >> 1;               // even waves: output ntile; odd: gx ntile

  // ---- Wh A-fragments -> registers (ALL waves; K-chunks w*8..w*8+7) ----
  f16x8 whf[16];
  #pragma unroll
  for (int n = 0; n < 2; ++n)
    #pragma unroll
    for (int i = 0; i < 8; ++i) {
      const float* p = Wh + (size_t)(j0 + n * 16 + col) * HH + ((w << 3) + i) * 32 + quad * 8;
      whf[n * 8 + i] = cvt8(*reinterpret_cast<const float4*>(p),
                            *reinterpret_cast<const float4*>(p + 4));
    }
  // ---- Wx A-fragments (odd waves; [gate][ks]) ----
  f16x8 wxf[16];
  if (w & 1) {
    #pragma unroll
    for (int g2 = 0; g2 < 2; ++g2)
      #pragma unroll
      for (int ks = 0; ks < 8; ++ks) {
        const float* p = Wx + (size_t)(g2 * HH + j0 + nt * 16 + col) * ID + ks * 32 + quad * 8;
        wxf[g2 * 8 + ks] = cvt8(*reinterpret_cast<const float4*>(p),
                                *reinterpret_cast<const float4*>(p + 4));
      }
  }

  // ---- prologue: stage x(0)->slot0, x(1)->slot1 ----
  for (int s = 0; s < 2; ++s)
    for (int c = tid; c < 1024; c += 256) {
      int row = c >> 6, k4 = c & 63;
      float4 v = *reinterpret_cast<const float4*>(
          x + ((size_t)(b0 + row) * TT + s) * ID + k4 * 4);
      store4h((f16*)(xbuf + s * 8192 + row * 512 + SWZ(row, k4 * 8)), v.x, v.y, v.z, v.w);
    }
  __syncthreads();

  // ---- prologue gx(0) (odd waves), parity 0 ----
  if (w & 1) {
    const char* pxb = xbuf + col * 512 + ((quad * 16) ^ ((col & 3) << 4));
    f32x4 a0 = {0,0,0,0}, a1 = {0,0,0,0};
    #pragma unroll
    for (int ks = 0; ks < 8; ++ks) {
      f16x8 bfr = *reinterpret_cast<const f16x8*>(pxb + ks * 64);
      a0 = MFMA16(wxf[ks], bfr, a0);
      a1 = MFMA16(wxf[8 + ks], bfr, a1);
    }
    put_tile(gxch + nt * 272, a0, lane);
    put_tile(gxch + (2 + nt) * 272, a1, lane);
  }

  // even-wave pointwise constants (j = j0 + nt*16 + row4 + r)
  float4 bh4 = {0,0,0,0}, bxr4 = {0,0,0,0}, bxi4 = {0,0,0,0};
  if (!(w & 1)) {
    bh4  = *reinterpret_cast<const float4*>(bh + j0 + nt * 16 + row4);
    bxr4 = *reinterpret_cast<const float4*>(bx + j0 + nt * 16 + row4);
    bxi4 = *reinterpret_cast<const float4*>(bx + HH + j0 + nt * 16 + row4);
  }
  float hm[4] = {0.f, 0.f, 0.f, 0.f};     // h[b0+col][j0+nt*16+row4+r]

  // invariant addresses
  const unsigned gvo = (unsigned)(col * 64 + quad * 16);
  const u64 hb0 = (u64)((const char*)hbuf + (((size_t)g * 32 + (w << 3)) << 10)) + gvo;
  const u64 hb1 = hb0 + (256ull << 10);
  const u64 pb0 = (u64)((char*)hbuf + (((size_t)g * 32 + cw) << 10))
                  + (unsigned)(col * 64 + nt * 32 + quad * 8);
  const u64 pb1 = pb0 + (256ull << 10);
  // PACKED flags: group g occupies ints [g*64, g*64+64) = 4 cachelines.
  int* myflag = flags + g * 64 + cw * 2 + nt;
  const int* pollp = flags + g * 64 + lane;          // all 64 lanes, 1 flag each
  const u64 pollmask = 0xFFFFull << (w * 16);        // writers w*8..w*8+7, both nt

  for (int t = 0; t < TT; ++t) {
    const int p = t & 1;
    // ======== region A: packed poll -> gather 8 chunks -> 16 MFMAs ========
    f32x4 acc0 = {0,0,0,0}, acc1 = {0,0,0,0};
    if (t > 0) {
      int v; u64 rdy;
      do { v = __hip_atomic_load(pollp, __ATOMIC_RELAXED, __HIP_MEMORY_SCOPE_SYSTEM);
           rdy = __ballot(v >= t);
      } while ((rdy & pollmask) != pollmask);

      u64 ad0 = p ? hb1 : hb0;
      u64 ad1 = ad0 + 4096;
      f32x4 f0, f1, f2, f3, f4, f5, f6, f7;
      asm volatile(
        "global_load_dwordx4 %0, %8, off sc0 sc1\n\t"
        "global_load_dwordx4 %1, %8, off offset:1024 sc0 sc1\n\t"
        "global_load_dwordx4 %2, %8, off offset:2048 sc0 sc1\n\t"
        "global_load_dwordx4 %3, %8, off offset:3072 sc0 sc1\n\t"
        "global_load_dwordx4 %4, %9, off sc0 sc1\n\t"
        "global_load_dwordx4 %5, %9, off offset:1024 sc0 sc1\n\t"
        "global_load_dwordx4 %6, %9, off offset:2048 sc0 sc1\n\t"
        "global_load_dwordx4 %7, %9, off offset:3072 sc0 sc1\n\t"
        "s_waitcnt vmcnt(0)"
        : "=&v"(f0), "=&v"(f1), "=&v"(f2), "=&v"(f3),
          "=&v"(f4), "=&v"(f5), "=&v"(f6), "=&v"(f7)
        : "v"(ad0), "v"(ad1) : "memory");

      #define STEPM(i, F) { f16x8 bf_ = *reinterpret_cast<f16x8*>(&F); \
        acc0 = MFMA16(whf[i], bf_, acc0); acc1 = MFMA16(whf[8 + (i)], bf_, acc1); }
      STEPM(0, f0) STEPM(1, f1) STEPM(2, f2) STEPM(3, f3)
      STEPM(4, f4) STEPM(5, f5) STEPM(6, f6) STEPM(7, f7)
      #undef STEPM
    }
    // export partials (slot = src wave); even waves keep own-nt in register
    float* ghp = ghT + p * 2176;
    if (w == 0)      { put_tile(ghp + (4 + 0) * 272, acc1, lane); }
    else if (w == 1) { put_tile(ghp + 1 * 272, acc0, lane);
                       put_tile(ghp + (4 + 1) * 272, acc1, lane); }
    else if (w == 2) { put_tile(ghp + 2 * 272, acc0, lane); }
    else             { put_tile(ghp + 3 * 272, acc0, lane);
                       put_tile(ghp + (4 + 3) * 272, acc1, lane); }

    __syncthreads();                                  // the ONE barrier/step

    // ======== region B ========
    if (!(w & 1)) {
      // reduce 3 partials + own, pointwise, publish, flag
      const float* basep = ghp + nt * 4 * 272;
      const float* s0 = basep + ((w == 0) ? 1 : 0) * 272;
      const float* s1 = basep + ((w == 0) ? 2 : 1) * 272;
      const float* s2 = basep + 3 * 272;
      const float* gxr = gxch + p * 1088 + nt * 272;
      const float* gxi = gxch + p * 1088 + (2 + nt) * 272;
      f32x4 own = (w == 0) ? acc0 : acc1;
      float hn[4];
      #pragma unroll
      for (int r = 0; r < 4; ++r) {
        int idx = (row4 + r) * 17 + col;
        float ghf = own[r] + s0[idx] + s1[idx] + s2[idx] + ((const float*)&bh4)[r];
        float ir  = gxr[idx] + ((const float*)&bxr4)[r];
        float ii  = gxi[idx] + ((const float*)&bxi4)[r];
        float rg  = 1.f / (1.f + __expf(-ir));
        float ig  = 1.f / (1.f + __expf(-ii));
        float z   = rg * ghf;
        z = fminf(fmaxf(z, -15.f), 15.f);
        float e   = __expf(-2.f * z);
        float ng  = (1.f - e) / (1.f + e);
        float h_  = ng + ig * (hm[r] - ng);
        hm[r] = h_; hn[r] = h_;
      }
      union { f16 h[4]; u64 uu; } pk;
      pk.h[0] = (f16)hn[0]; pk.h[1] = (f16)hn[1]; pk.h[2] = (f16)hn[2]; pk.h[3] = (f16)hn[3];
      u64* adp = (u64*)(p ? pb0 : pb1);               // h(t+1) -> parity (t+1)&1
      __hip_atomic_store(adp, pk.uu, __ATOMIC_RELAXED, __HIP_MEMORY_SCOPE_SYSTEM);
      asm volatile("s_waitcnt vmcnt(0)" ::: "memory"); // data before flag
      if (lane == 0)
        __hip_atomic_store(myflag, t + 1, __ATOMIC_RELAXED, __HIP_MEMORY_SCOPE_SYSTEM);
    } else {
      // gx(t+1) -> gxch parity (t+1)&1
      if (t + 1 < TT) {
        const char* pxb = xbuf + ((t + 1) & 1) * 8192 + col * 512
                          + ((quad * 16) ^ ((col & 3) << 4));
        f32x4 a0 = {0,0,0,0}, a1 = {0,0,0,0};
        #pragma unroll
        for (int ks = 0; ks < 8; ++ks) {
          f16x8 bfr = *reinterpret_cast<const f16x8*>(pxb + ks * 64);
          a0 = MFMA16(wxf[ks], bfr, a0);
          a1 = MFMA16(wxf[8 + ks], bfr, a1);
        }
        float* gdst = gxch + ((t + 1) & 1) * 1088;
        put_tile(gdst + nt * 272, a0, lane);
        put_tile(gdst + (2 + nt) * 272, a1, lane);
      }
      // x(t+2) prefetch -> slot t&1 (w1 rows 0-7, w3 rows 8-15)
      if (t + 2 < TT) {
        char* xd = xbuf + p * 8192;
        #pragma unroll
        for (int it = 0; it < 8; ++it) {
          int row = nt * 8 + it;
          float4 v = *reinterpret_cast<const float4*>(
              x + ((size_t)(b0 + row) * TT + (t + 2)) * ID + lane * 4);
          store4h((f16*)(xd + row * 512 + SWZ(row, lane * 8)), v.x, v.y, v.z, v.w);
        }
      }
    }
  }

  // ---- final h export ----
  if (!(w & 1)) {
    float4 o; o.x = hm[0]; o.y = hm[1]; o.z = hm[2]; o.w = hm[3];
    *reinterpret_cast<float4*>(hfin + (size_t)(b0 + col) * HH + j0 + nt * 16 + row4) = o;
  }
}

// out[b][o] = hfin[b][:] . Wfc[o][:] + bfc[o];  128x256, K=1024.
__global__ __launch_bounds__(64) void fc_kernel(
    const float* __restrict__ hfin, const float* __restrict__ Wfc,
    const float* __restrict__ bfc, float* __restrict__ out)
{
  const int lane = threadIdx.x;
  const int mb = blockIdx.x >> 4, nb = blockIdx.x & 15;
  const int col = lane & 15, row4 = (lane >> 4) * 4;
  const float* pa = hfin + (size_t)(mb * 16 + (lane & 15)) * HH + (lane >> 4) * 8;
  const float* pb = Wfc  + (size_t)(nb * 16 + (lane & 15)) * HH + (lane >> 4) * 8;
  f32x4 acc = {0.f, 0.f, 0.f, 0.f};
  for (int kc = 0; kc < 32; ++kc) {
    f16x8 a, b;
    #pragma unroll
    for (int e = 0; e < 8; ++e) {
      a[e] = (f16)pa[kc * 32 + e];
      b[e] = (f16)pb[kc * 32 + e];
    }
    acc = __builtin_amdgcn_mfma_f32_16x16x32_f16(a, b, acc, 0, 0, 0);
  }
  float bias = bfc[nb * 16 + col];
  #pragma unroll
  for (int r = 0; r < 4; ++r)
    out[(size_t)(mb * 16 + row4 + r) * 256 + nb * 16 + col] = acc[r] + bias;
}

extern "C" void kernel_launch(void* const* d_in, const int* in_sizes, int n_in,
                              void* d_out, int out_size, void* d_ws, size_t ws_size,
                              hipStream_t stream) {
  const float* x   = (const float*)d_in[0];
  const float* Wx  = (const float*)d_in[1];
  const float* bx  = (const float*)d_in[2];
  const float* Wh  = (const float*)d_in[3];
  const float* bh  = (const float*)d_in[4];
  const float* Wfc = (const float*)d_in[5];
  const float* bfc = (const float*)d_in[6];
  float* out = (float*)d_out;

  char* ws = (char*)d_ws;
  f16*   hbuf  = (f16*)ws;                 // 512KB chunk exchange
  float* hfin  = (float*)(ws + 524288);    // 512KB
  int*   flags = (int*)(ws + 1048576);     // packed: 8 groups x 256B = 2KB

  hipMemsetAsync(flags, 0, 4096, stream);  // stamps monotone within one run

  (void)hipFuncSetAttribute((const void*)rnn_core,
                            hipFuncAttributeMaxDynamicSharedMemorySize, LDS_SIZE);

  void* args[8];
  args[0] = (void*)&x;    args[1] = (void*)&Wx;   args[2] = (void*)&bx;
  args[3] = (void*)&Wh;   args[4] = (void*)&bh;   args[5] = (void*)&hbuf;
  args[6] = (void*)&hfin; args[7] = (void*)&flags;
  hipError_t err = hipLaunchCooperativeKernel((void*)rnn_core, dim3(256), dim3(256),
                                              args, LDS_SIZE, stream);
  if (err != hipSuccess) {
    rnn_core<<<dim3(256), dim3(256), LDS_SIZE, stream>>>(x, Wx, bx, Wh, bh, hbuf, hfin, flags);
  }

  fc_kernel<<<dim3(128), dim3(64), 0, stream>>>(hfin, Wfc, bfc, out);
}

// Round 15
// 3137.164 us; speedup vs baseline: 1.9327x; 1.9327x over previous
//
#include <hip/hip_runtime.h>
#include <hip/hip_fp16.h>

// IGIRNN persistent-scan kernel, round 15 = round 8 RESTORED (best: 3.08ms)
// + ONE micro fix: LDS exchange-tile stride 17 -> 20 f32.
// r14 lesson (packed flags, 2x regression): pollers may share cachelines,
// WRITERS must own lines -- r8's 64B-strided flags restored verbatim.
// Bank math for the 17-stride tiles: banks = (17r + c + 4q) mod 32 -> 4-way
// conflict (352 conflict-cyc/WG/step, 5% of step; SQ_LDS_BANK_CONFLICT
// 9.2e7). Stride 20: banks = (20r + c + 16*(q&1)) mod 32 -> q-pairs split
// across bank halves, exactly 2 lanes/bank = free (m136). Applies to
// put_tile writes + reduce reads + gx reads. Everything else is r8.

#define BB 128
#define TT 1024
#define ID 256
#define HH 1024

using f16   = _Float16;
using f16x8 = __attribute__((ext_vector_type(8))) _Float16;
using f32x4 = __attribute__((ext_vector_type(4))) float;
typedef unsigned long long u64;

#define TS 320            // f32 tile stride-row... tile = [16][TS/16=20] pattern: idx=(row)*20+col, tile block = 320 f32
// LDS (bytes)
#define OFF_X    0        // x   [2][16][512B] f16, SWZ        = 16384
#define OFF_GX   16384    // gx  [2][4][TS] f32                = 10240
#define OFF_GH   26624    // ghT [2][2][4][TS] f32             = 20480
#define LDS_SIZE 47104

#define SWZ(row, kbyte) ((kbyte) ^ (((row) & 3) << 4))
#define MFMA16(a, b, c) __builtin_amdgcn_mfma_f32_16x16x32_f16(a, b, c, 0, 0, 0)

static __device__ __forceinline__ void store4h(f16* dst, float a, float b, float c, float d) {
  union { f16 h[4]; u64 u; } p;
  p.h[0] = (f16)a; p.h[1] = (f16)b; p.h[2] = (f16)c; p.h[3] = (f16)d;
  *reinterpret_cast<u64*>(dst) = p.u;
}

static __device__ __forceinline__ f16x8 cvt8(float4 a, float4 b) {
  f16x8 r;
  r[0] = (f16)a.x; r[1] = (f16)a.y; r[2] = (f16)a.z; r[3] = (f16)a.w;
  r[4] = (f16)b.x; r[5] = (f16)b.y; r[6] = (f16)b.z; r[7] = (f16)b.w;
  return r;
}

static __device__ __forceinline__ void put_tile(float* dst, f32x4 v, int lane) {
  const int c = lane & 15, r4 = (lane >> 4) * 4;
  #pragma unroll
  for (int r = 0; r < 4; ++r) dst[(r4 + r) * 20 + c] = v[r];   // stride 20: 2-way free
}

__global__ __launch_bounds__(256, 1) void rnn_core(
    const float* __restrict__ x, const float* __restrict__ Wx, const float* __restrict__ bx,
    const float* __restrict__ Wh, const float* __restrict__ bh,
    f16* __restrict__ hbuf,      // [2 slot][8 grp][32 wg][1KB chunk] = 512KB
    float* __restrict__ hfin,    // [128][1024] f32
    int* __restrict__ flags)     // [8][32][2] stamps, 64B-strided (r8 layout)
{
  extern __shared__ char lds[];
  char*  xbuf = lds + OFF_X;
  float* gxch = (float*)(lds + OFF_GX);   // [2][4][TS], q = gate*2 + nt
  float* ghT  = (float*)(lds + OFF_GH);   // [2][2][4][TS]: [parity][nt][src]

  const int tid  = threadIdx.x;
  const int lane = tid & 63;
  const int w    = tid >> 6;
  const int g    = blockIdx.x & 7;
  const int cw   = blockIdx.x >> 3;
  const int b0   = g * 16;
  const int j0   = cw * 32;
  const int col  = lane & 15;
  const int quad = lane >> 4;
  const int row4 = quad * 4;
  const int nt   = w >> 1;               // even waves: output ntile; odd: gx ntile

  // ---- Wh A-fragments -> registers (ALL waves; K-chunks w*8..w*8+7) ----
  f16x8 whf[16];
  #pragma unroll
  for (int n = 0; n < 2; ++n)
    #pragma unroll
    for (int i = 0; i < 8; ++i) {
      const float* p = Wh + (size_t)(j0 + n * 16 + col) * HH + ((w << 3) + i) * 32 + quad * 8;
      whf[n * 8 + i] = cvt8(*reinterpret_cast<const float4*>(p),
                            *reinterpret_cast<const float4*>(p + 4));
    }
  // ---- Wx A-fragments (odd waves; [gate][ks]) ----
  f16x8 wxf[16];
  if (w & 1) {
    #pragma unroll
    for (int g2 = 0; g2 < 2; ++g2)
      #pragma unroll
      for (int ks = 0; ks < 8; ++ks) {
        const float* p = Wx + (size_t)(g2 * HH + j0 + nt * 16 + col) * ID + ks * 32 + quad * 8;
        wxf[g2 * 8 + ks] = cvt8(*reinterpret_cast<const float4*>(p),
                                *reinterpret_cast<const float4*>(p + 4));
      }
  }

  // ---- prologue: stage x(0)->slot0, x(1)->slot1 ----
  for (int s = 0; s < 2; ++s)
    for (int c = tid; c < 1024; c += 256) {
      int row = c >> 6, k4 = c & 63;
      float4 v = *reinterpret_cast<const float4*>(
          x + ((size_t)(b0 + row) * TT + s) * ID + k4 * 4);
      store4h((f16*)(xbuf + s * 8192 + row * 512 + SWZ(row, k4 * 8)), v.x, v.y, v.z, v.w);
    }
  __syncthreads();

  // ---- prologue gx(0) (odd waves), parity 0 ----
  if (w & 1) {
    const char* pxb = xbuf + col * 512 + ((quad * 16) ^ ((col & 3) << 4));
    f32x4 a0 = {0,0,0,0}, a1 = {0,0,0,0};
    #pragma unroll
    for (int ks = 0; ks < 8; ++ks) {
      f16x8 bfr = *reinterpret_cast<const f16x8*>(pxb + ks * 64);
      a0 = MFMA16(wxf[ks], bfr, a0);
      a1 = MFMA16(wxf[8 + ks], bfr, a1);
    }
    put_tile(gxch + nt * TS, a0, lane);
    put_tile(gxch + (2 + nt) * TS, a1, lane);
  }

  // even-wave pointwise constants (j = j0 + nt*16 + row4 + r)
  float4 bh4 = {0,0,0,0}, bxr4 = {0,0,0,0}, bxi4 = {0,0,0,0};
  if (!(w & 1)) {
    bh4  = *reinterpret_cast<const float4*>(bh + j0 + nt * 16 + row4);
    bxr4 = *reinterpret_cast<const float4*>(bx + j0 + nt * 16 + row4);
    bxi4 = *reinterpret_cast<const float4*>(bx + HH + j0 + nt * 16 + row4);
  }
  float hm[4] = {0.f, 0.f, 0.f, 0.f};     // h[b0+col][j0+nt*16+row4+r]

  // invariant addresses (r8 verbatim)
  const unsigned gvo = (unsigned)(col * 64 + quad * 16);
  const u64 hb0 = (u64)((const char*)hbuf + (((size_t)g * 32 + (w << 3)) << 10)) + gvo;
  const u64 hb1 = hb0 + (256ull << 10);
  const u64 pb0 = (u64)((char*)hbuf + (((size_t)g * 32 + cw) << 10))
                  + (unsigned)(col * 64 + nt * 32 + quad * 8);
  const u64 pb1 = pb0 + (256ull << 10);
  int* myflag = flags + ((g * 32 + cw) * 2 + nt) * 16;
  const int* pollp = flags + ((g * 32 + (w << 3) + (lane & 7)) * 2 + ((lane >> 3) & 1)) * 16;

  for (int t = 0; t < TT; ++t) {
    const int p = t & 1;
    // ======== region A: poll 16 flags -> gather 8 chunks -> 16 MFMAs ========
    f32x4 acc0 = {0,0,0,0}, acc1 = {0,0,0,0};
    if (t > 0) {
      int v;
      do { v = (lane < 16)
               ? __hip_atomic_load(pollp, __ATOMIC_RELAXED, __HIP_MEMORY_SCOPE_SYSTEM) : t;
      } while (!__all(v >= t));

      u64 ad0 = p ? hb1 : hb0;
      u64 ad1 = ad0 + 4096;
      f32x4 f0, f1, f2, f3, f4, f5, f6, f7;
      asm volatile(
        "global_load_dwordx4 %0, %8, off sc0 sc1\n\t"
        "global_load_dwordx4 %1, %8, off offset:1024 sc0 sc1\n\t"
        "global_load_dwordx4 %2, %8, off offset:2048 sc0 sc1\n\t"
        "global_load_dwordx4 %3, %8, off offset:3072 sc0 sc1\n\t"
        "global_load_dwordx4 %4, %9, off sc0 sc1\n\t"
        "global_load_dwordx4 %5, %9, off offset:1024 sc0 sc1\n\t"
        "global_load_dwordx4 %6, %9, off offset:2048 sc0 sc1\n\t"
        "global_load_dwordx4 %7, %9, off offset:3072 sc0 sc1\n\t"
        "s_waitcnt vmcnt(0)"
        : "=&v"(f0), "=&v"(f1), "=&v"(f2), "=&v"(f3),
          "=&v"(f4), "=&v"(f5), "=&v"(f6), "=&v"(f7)
        : "v"(ad0), "v"(ad1) : "memory");

      #define STEPM(i, F) { f16x8 bf_ = *reinterpret_cast<f16x8*>(&F); \
        acc0 = MFMA16(whf[i], bf_, acc0); acc1 = MFMA16(whf[8 + (i)], bf_, acc1); }
      STEPM(0, f0) STEPM(1, f1) STEPM(2, f2) STEPM(3, f3)
      STEPM(4, f4) STEPM(5, f5) STEPM(6, f6) STEPM(7, f7)
      #undef STEPM
    }
    // export partials (slot = nt*4 + src wave); even waves keep own-nt in reg
    float* ghp = ghT + p * (8 * TS);
    if (w == 0)      { put_tile(ghp + (4 + 0) * TS, acc1, lane); }
    else if (w == 1) { put_tile(ghp + 1 * TS, acc0, lane);
                       put_tile(ghp + (4 + 1) * TS, acc1, lane); }
    else if (w == 2) { put_tile(ghp + 2 * TS, acc0, lane); }
    else             { put_tile(ghp + 3 * TS, acc0, lane);
                       put_tile(ghp + (4 + 3) * TS, acc1, lane); }

    __syncthreads();                                  // the ONE barrier/step

    // ======== region B ========
    if (!(w & 1)) {
      // reduce 3 partials + own, pointwise, publish, flag
      const float* basep = ghp + nt * 4 * TS;
      const float* s0 = basep + ((w == 0) ? 1 : 0) * TS;
      const float* s1 = basep + ((w == 0) ? 2 : 1) * TS;
      const float* s2 = basep + 3 * TS;
      const float* gxr = gxch + p * (4 * TS) + nt * TS;
      const float* gxi = gxch + p * (4 * TS) + (2 + nt) * TS;
      f32x4 own = (w == 0) ? acc0 : acc1;
      float hn[4];
      #pragma unroll
      for (int r = 0; r < 4; ++r) {
        int idx = (row4 + r) * 20 + col;
        float ghf = own[r] + s0[idx] + s1[idx] + s2[idx] + ((const float*)&bh4)[r];
        float ir  = gxr[idx] + ((const float*)&bxr4)[r];
        float ii  = gxi[idx] + ((const float*)&bxi4)[r];
        float rg  = 1.f / (1.f + __expf(-ir));
        float ig  = 1.f / (1.f + __expf(-ii));
        float z   = rg * ghf;
        z = fminf(fmaxf(z, -15.f), 15.f);
        float e   = __expf(-2.f * z);
        float ng  = (1.f - e) / (1.f + e);
        float h_  = ng + ig * (hm[r] - ng);
        hm[r] = h_; hn[r] = h_;
      }
      union { f16 h[4]; u64 uu; } pk;
      pk.h[0] = (f16)hn[0]; pk.h[1] = (f16)hn[1]; pk.h[2] = (f16)hn[2]; pk.h[3] = (f16)hn[3];
      u64* adp = (u64*)(p ? pb0 : pb1);               // h(t+1) -> parity (t+1)&1
      __hip_atomic_store(adp, pk.uu, __ATOMIC_RELAXED, __HIP_MEMORY_SCOPE_SYSTEM);
      asm volatile("s_waitcnt vmcnt(0)" ::: "memory"); // data before flag
      if (lane == 0)
        __hip_atomic_store(myflag, t + 1, __ATOMIC_RELAXED, __HIP_MEMORY_SCOPE_SYSTEM);
    } else {
      // gx(t+1) -> gxch parity (t+1)&1
      if (t + 1 < TT) {
        const char* pxb = xbuf + ((t + 1) & 1) * 8192 + col * 512
                          + ((quad * 16) ^ ((col & 3) << 4));
        f32x4 a0 = {0,0,0,0}, a1 = {0,0,0,0};
        #pragma unroll
        for (int ks = 0; ks < 8; ++ks) {
          f16x8 bfr = *reinterpret_cast<const f16x8*>(pxb + ks * 64);
          a0 = MFMA16(wxf[ks], bfr, a0);
          a1 = MFMA16(wxf[8 + ks], bfr, a1);
        }
        float* gdst = gxch + ((t + 1) & 1) * (4 * TS);
        put_tile(gdst + nt * TS, a0, lane);
        put_tile(gdst + (2 + nt) * TS, a1, lane);
      }
      // x(t+2) prefetch -> slot t&1 (w1 rows 0-7, w3 rows 8-15)
      if (t + 2 < TT) {
        char* xd = xbuf + p * 8192;
        #pragma unroll
        for (int it = 0; it < 8; ++it) {
          int row = nt * 8 + it;
          float4 v = *reinterpret_cast<const float4*>(
              x + ((size_t)(b0 + row) * TT + (t + 2)) * ID + lane * 4);
          store4h((f16*)(xd + row * 512 + SWZ(row, lane * 8)), v.x, v.y, v.z, v.w);
        }
      }
    }
  }

  // ---- final h export ----
  if (!(w & 1)) {
    float4 o; o.x = hm[0]; o.y = hm[1]; o.z = hm[2]; o.w = hm[3];
    *reinterpret_cast<float4*>(hfin + (size_t)(b0 + col) * HH + j0 + nt * 16 + row4) = o;
  }
}

// out[b][o] = hfin[b][:] . Wfc[o][:] + bfc[o];  128x256, K=1024.
__global__ __launch_bounds__(64) void fc_kernel(
    const float* __restrict__ hfin, const float* __restrict__ Wfc,
    const float* __restrict__ bfc, float* __restrict__ out)
{
  const int lane = threadIdx.x;
  const int mb = blockIdx.x >> 4, nb = blockIdx.x & 15;
  const int col = lane & 15, row4 = (lane >> 4) * 4;
  const float* pa = hfin + (size_t)(mb * 16 + (lane & 15)) * HH + (lane >> 4) * 8;
  const float* pb = Wfc  + (size_t)(nb * 16 + (lane & 15)) * HH + (lane >> 4) * 8;
  f32x4 acc = {0.f, 0.f, 0.f, 0.f};
  for (int kc = 0; kc < 32; ++kc) {
    f16x8 a, b;
    #pragma unroll
    for (int e = 0; e < 8; ++e) {
      a[e] = (f16)pa[kc * 32 + e];
      b[e] = (f16)pb[kc * 32 + e];
    }
    acc = __builtin_amdgcn_mfma_f32_16x16x32_f16(a, b, acc, 0, 0, 0);
  }
  float bias = bfc[nb * 16 + col];
  #pragma unroll
  for (int r = 0; r < 4; ++r)
    out[(size_t)(mb * 16 + row4 + r) * 256 + nb * 16 + col] = acc[r] + bias;
}

extern "C" void kernel_launch(void* const* d_in, const int* in_sizes, int n_in,
                              void* d_out, int out_size, void* d_ws, size_t ws_size,
                              hipStream_t stream) {
  const float* x   = (const float*)d_in[0];
  const float* Wx  = (const float*)d_in[1];
  const float* bx  = (const float*)d_in[2];
  const float* Wh  = (const float*)d_in[3];
  const float* bh  = (const float*)d_in[4];
  const float* Wfc = (const float*)d_in[5];
  const float* bfc = (const float*)d_in[6];
  float* out = (float*)d_out;

  char* ws = (char*)d_ws;
  f16*   hbuf  = (f16*)ws;                 // 512KB chunk exchange
  float* hfin  = (float*)(ws + 524288);    // 512KB
  int*   flags = (int*)(ws + 1048576);     // 32KB (r8: [8][32][2] x 64B)

  hipMemsetAsync(flags, 0, 32768, stream); // stamps monotone within one run

  (void)hipFuncSetAttribute((const void*)rnn_core,
                            hipFuncAttributeMaxDynamicSharedMemorySize, LDS_SIZE);

  void* args[8];
  args[0] = (void*)&x;    args[1] = (void*)&Wx;   args[2] = (void*)&bx;
  args[3] = (void*)&Wh;   args[4] = (void*)&bh;   args[5] = (void*)&hbuf;
  args[6] = (void*)&hfin; args[7] = (void*)&flags;
  hipError_t err = hipLaunchCooperativeKernel((void*)rnn_core, dim3(256), dim3(256),
                                              args, LDS_SIZE, stream);
  if (err != hipSuccess) {
    rnn_core<<<dim3(256), dim3(256), LDS_SIZE, stream>>>(x, Wx, bx, Wh, bh, hbuf, hfin, flags);
  }

  fc_kernel<<<dim3(128), dim3(64), 0, stream>>>(hfin, Wfc, bfc, out);
}